// Round 1
// 214.610 us; speedup vs baseline: 1.0159x; 1.0159x over previous
//
#include <hip/hip_runtime.h>
#include <hip/hip_bf16.h>
#include <math.h>

#define NROWS 8192
#define DDIM  4096
#define NEXP  64
#define KSPLIT 16
#define KCHUNK (DDIM / KSPLIT)   // 256
#define KSTEPS (KCHUNK / 32)     // 8  -- compile-time: allocator pipelines it

typedef __attribute__((ext_vector_type(8))) short bf16x8;
typedef __attribute__((ext_vector_type(4))) float f32x4;

__device__ inline unsigned short bf16_rne(float f) {
    unsigned u = __builtin_bit_cast(unsigned, f);
    u += 0x7FFF + ((u >> 16) & 1);
    return (unsigned short)(u >> 16);
}

// split 8 fp32 -> hi/lo bf16 (x = hi + lo + r, |r| <= 2^-18|x|)
__device__ inline void split8(const float* xf, bf16x8& hi, bf16x8& lo) {
#pragma unroll
    for (int j = 0; j < 8; j++) {
        const unsigned short h = bf16_rne(xf[j]);
        const float hf = __builtin_bit_cast(float, (unsigned)h << 16);
        hi[j] = (short)h;
        lo[j] = (short)bf16_rne(xf[j] - hf);
    }
}

// Preconvert W (64 x 4096 fp32) into MFMA B-fragment-linear bf16 hi/lo:
// frag elem j of lane l, tile t, k-chunk kc = B[k=kc*32+(l>>4)*8+j][n=t*16+(l&15)]
// at ((kc*4+t)*64+l)*8. ~1 MB total -> L2/L3-resident for the GEMM.
// ALSO zeroes the 2 MB logits accumulator (ws is poisoned every iteration,
// and the GEMM now accumulates into it with atomics).
__global__ __launch_bounds__(256) void wfrag_kernel(
    const float* __restrict__ w, unsigned short* __restrict__ whi,
    unsigned short* __restrict__ wlo, float* __restrict__ logits)
{
    const int kc = blockIdx.x;            // 0..127
    const int t  = threadIdx.x >> 6;      // n-tile 0..3
    const int l  = threadIdx.x & 63;
    const int e  = t * 16 + (l & 15);
    const int k0 = kc * 32 + ((l >> 4) * 8);
    const float* p = w + (size_t)e * DDIM + k0;
    float xf[8];
    *(float4*)&xf[0] = *(const float4*)p;
    *(float4*)&xf[4] = *(const float4*)(p + 4);
    bf16x8 hi, lo;
    split8(xf, hi, lo);
    const size_t off = ((size_t)(kc * 4 + t) * 64 + l) * 8;
    *(bf16x8*)(whi + off) = hi;
    *(bf16x8*)(wlo + off) = lo;

    // zero logits: 8192*64 floats = 131072 float4; 128 blk * 256 thr * 4 = 131072
    const float4 z = {0.f, 0.f, 0.f, 0.f};
    float4* lz = (float4*)logits;
    const int base = (blockIdx.x * 256 + threadIdx.x) * 4;
#pragma unroll
    for (int j = 0; j < 4; j++) lz[base + j] = z;
}

// GEMM: no LDS/barriers. Block = 4 waves; wave = 32 rows (2 m-tiles) x 64
// experts -> each B fragment feeds 2 MFMAs (B L2 traffic halved vs 16-row).
// ALL trip counts compile-time (R7 lesson: runtime ksplit made the allocator
// squeeze to 56 VGPR and spill 120 MB of scratch). Live set ~124 regs.
// Per k32-step: 4 x-loads (HBM, double-buffered) + 8 B-loads (L2, single-
// buffered, hidden behind split8 VALU) + 24 MFMA.
// Epilogue: split-K partials accumulated with HW f32 atomics into the 2 MB
// logits buffer (16 updates/address, L2/LLC-resident) instead of a 32 MB
// materialized part[] round-trip (-64 MB HBM traffic).
__global__ __launch_bounds__(256) void gemm_partial_kernel(
    const float* __restrict__ x, const unsigned short* __restrict__ whi,
    const unsigned short* __restrict__ wlo, float* __restrict__ logits)
{
    const int tid = threadIdx.x;
    const int wv  = tid >> 6;
    const int l   = tid & 63;
    const int q   = l >> 4;
    const int col = l & 15;
    const int r0  = blockIdx.x * 128 + wv * 32;
    const int kh  = blockIdx.y;
    const int kb  = kh * KCHUNK;

    const float* xp0 = x + (size_t)(r0 + col) * DDIM + kb + q * 8;
    const float* xp1 = xp0 + (size_t)16 * DDIM;
    const unsigned short* bhp = whi + ((size_t)(kb / 32) * 4 * 64 + l) * 8;
    const unsigned short* blp = wlo + ((size_t)(kb / 32) * 4 * 64 + l) * 8;

    f32x4 acc[2][4];
#pragma unroll
    for (int m = 0; m < 2; m++)
#pragma unroll
        for (int t = 0; t < 4; t++) acc[m][t] = f32x4{0, 0, 0, 0};

    float xf[2][2][8];                  // [buf][mtile][elem]
    *(float4*)&xf[0][0][0] = *(const float4*)(xp0);
    *(float4*)&xf[0][0][4] = *(const float4*)(xp0 + 4);
    *(float4*)&xf[0][1][0] = *(const float4*)(xp1);
    *(float4*)&xf[0][1][4] = *(const float4*)(xp1 + 4);

    for (int s = 0; s < KSTEPS; s++) {
        const int cur = s & 1, nxt = cur ^ 1;

        bf16x8 bh[4], bl[4];
        const unsigned short* bhs = bhp + (size_t)s * 4 * 64 * 8;
        const unsigned short* bls = blp + (size_t)s * 4 * 64 * 8;
#pragma unroll
        for (int t = 0; t < 4; t++) {
            bh[t] = *(const bf16x8*)(bhs + (size_t)t * 64 * 8);
            bl[t] = *(const bf16x8*)(bls + (size_t)t * 64 * 8);
        }

        if (s + 1 < KSTEPS) {           // prefetch next step's x (HBM)
            const float* xn0 = xp0 + (s + 1) * 32;
            const float* xn1 = xp1 + (s + 1) * 32;
            *(float4*)&xf[nxt][0][0] = *(const float4*)(xn0);
            *(float4*)&xf[nxt][0][4] = *(const float4*)(xn0 + 4);
            *(float4*)&xf[nxt][1][0] = *(const float4*)(xn1);
            *(float4*)&xf[nxt][1][4] = *(const float4*)(xn1 + 4);
        }

        bf16x8 ah[2], al[2];
        split8(xf[cur][0], ah[0], al[0]);
        split8(xf[cur][1], ah[1], al[1]);
#pragma unroll
        for (int m = 0; m < 2; m++)
#pragma unroll
            for (int t = 0; t < 4; t++) {
                acc[m][t] = __builtin_amdgcn_mfma_f32_16x16x32_bf16(ah[m], bh[t], acc[m][t], 0, 0, 0);
                acc[m][t] = __builtin_amdgcn_mfma_f32_16x16x32_bf16(ah[m], bl[t], acc[m][t], 0, 0, 0);
                acc[m][t] = __builtin_amdgcn_mfma_f32_16x16x32_bf16(al[m], bh[t], acc[m][t], 0, 0, 0);
            }
    }

    // C/D: row = q*4 + r, col = l&15  (m89-verified mapping)
    // Fire-and-forget HW f32 atomics; 16 lanes (col) contiguous per (m,t,r)
    // -> 64 B coalesced atomic bursts.
#pragma unroll
    for (int m = 0; m < 2; m++)
#pragma unroll
        for (int t = 0; t < 4; t++)
#pragma unroll
            for (int r = 0; r < 4; r++)
                unsafeAtomicAdd(
                    &logits[(size_t)(r0 + m * 16 + q * 4 + r) * NEXP + t * 16 + col],
                    acc[m][t][r]);
}

// One wave per row: load logit, sigmoid, +bias, top-2 (tie -> lower index),
// normalize. out: [weights 2N][indices-as-float 2N][scores 64N]
__global__ __launch_bounds__(256) void gate_topk_kernel(
    const float* __restrict__ logits, const float* __restrict__ bias,
    float* __restrict__ out)
{
    const int tid = threadIdx.x;
    const int e   = tid & 63;
    const int row = blockIdx.x * 4 + (tid >> 6);
    const size_t idx = (size_t)row * NEXP + e;

    const float logit = logits[idx];
    const float score = 1.0f / (1.0f + expf(-logit));
    out[(size_t)4 * NROWS + idx] = score;           // scores

    const float biased = score + bias[e];

    float v = biased; int bi = e;
#pragma unroll
    for (int off = 32; off; off >>= 1) {
        const float ov = __shfl_xor(v, off);
        const int   oi = __shfl_xor(bi, off);
        if (ov > v || (ov == v && oi < bi)) { v = ov; bi = oi; }
    }
    const int i1 = bi;

    float v2 = (e == i1) ? -INFINITY : biased;
    int bi2 = e;
#pragma unroll
    for (int off = 32; off; off >>= 1) {
        const float ov = __shfl_xor(v2, off);
        const int   oi = __shfl_xor(bi2, off);
        if (ov > v2 || (ov == v2 && oi < bi2)) { v2 = ov; bi2 = oi; }
    }
    const int i2 = bi2;

    const float s1 = __shfl(score, i1);
    const float s2 = __shfl(score, i2);
    if (e == 0) {
        const float inv = 1.0f / (s1 + s2);
        out[(size_t)row * 2 + 0] = s1 * inv;
        out[(size_t)row * 2 + 1] = s2 * inv;
        out[(size_t)2 * NROWS + row * 2 + 0] = (float)i1;
        out[(size_t)2 * NROWS + row * 2 + 1] = (float)i2;
    }
}

extern "C" void kernel_launch(void* const* d_in, const int* in_sizes, int n_in,
                              void* d_out, int out_size, void* d_ws, size_t ws_size,
                              hipStream_t stream)
{
    const float* x    = (const float*)d_in[0];
    const float* w    = (const float*)d_in[1];
    const float* bias = (const float*)d_in[2];
    float* out  = (float*)d_out;

    float* logits = (float*)d_ws;                               // 2 MB
    const size_t logits_bytes = (size_t)NROWS * NEXP * 4;
    unsigned short* whi = (unsigned short*)((char*)d_ws + logits_bytes);  // 512 KB
    unsigned short* wlo = whi + (size_t)NEXP * DDIM;                      // 512 KB

    wfrag_kernel<<<DDIM / 32, 256, 0, stream>>>(w, whi, wlo, logits);
    dim3 g1(NROWS / 128, KSPLIT);
    gemm_partial_kernel<<<g1, 256, 0, stream>>>(x, whi, wlo, logits);
    gate_topk_kernel<<<NROWS / 4, 256, 0, stream>>>(logits, bias, out);
}